// Round 1
// baseline (702.490 us; speedup 1.0000x reference)
//
#include <hip/hip_runtime.h>
#include <hip/hip_bf16.h>
#include <stdint.h>

#define NN 8192
#define BB 256
#define EE 163840
#define HH 128
#define ZZ 256
#define LL 4

typedef unsigned short u16;
typedef float  f32x4  __attribute__((ext_vector_type(4)));
typedef __bf16 bf16x8 __attribute__((ext_vector_type(8)));

__device__ __forceinline__ u16 f2bf(float f) {
  union { float f; uint32_t u; } v; v.f = f;
  uint32_t r = v.u + 0x7fffu + ((v.u >> 16) & 1u);   // RNE, NaN not expected
  return (u16)(r >> 16);
}
__device__ __forceinline__ float silu_f(float x) {
  return x / (1.0f + __expf(-x));
}

// ---------------------------------------------------------------------------
// Small prep kernels
// ---------------------------------------------------------------------------
__global__ void k_hist(const int* __restrict__ ei, int* __restrict__ cnt) {
  const int e = blockIdx.x * 256 + threadIdx.x;
  if (e < EE) atomicAdd(&cnt[ei[e]], 1);
}

__global__ void k_latips(const float* __restrict__ lat, float* __restrict__ lip) {
  const int idx = blockIdx.x * 256 + threadIdx.x;
  if (idx >= BB * 9) return;
  const int b = idx / 9, j = idx % 9, i = j / 3, kk = j % 3;
  float s = 0.f;
#pragma unroll
  for (int m = 0; m < 3; ++m) s += lat[b * 9 + i * 3 + m] * lat[b * 9 + kk * 3 + m];
  lip[idx] = s;
}

// transpose edge weights to [n][k] bf16, K padded 325->352 with zeros
__global__ void k_wt1(const float* __restrict__ ew1, u16* __restrict__ wt1) {
  const int idx = blockIdx.x * 256 + threadIdx.x;   // L*128*352
  if (idx >= LL * 128 * 352) return;
  const int l = idx / (128 * 352), rem = idx % (128 * 352);
  const int n = rem / 352, k = rem % 352;
  wt1[idx] = (k < 325) ? f2bf(ew1[((size_t)l * 325 + k) * 128 + n]) : (u16)0;
}
__global__ void k_wt2(const float* __restrict__ ew2, u16* __restrict__ wt2) {
  const int idx = blockIdx.x * 256 + threadIdx.x;   // L*128*128
  if (idx >= LL * 128 * 128) return;
  const int l = idx >> 14, rem = idx & 16383;
  const int n = rem >> 7, k = rem & 127;
  wt2[idx] = f2bf(ew2[((size_t)l * 128 + k) * 128 + n]);
}

// per-layer, per-graph conditional adapter: c = silu(silu(cemb*w1+b1)@w2+b2)@mixin
__global__ __launch_bounds__(128) void k_adapt(
    const float* __restrict__ cemb, const float* __restrict__ aw1,
    const float* __restrict__ ab1, const float* __restrict__ aw2,
    const float* __restrict__ ab2, const float* __restrict__ mixin,
    float* __restrict__ call) {
  __shared__ float s1[128], s2[128];
  const int l = blockIdx.x >> 8, b = blockIdx.x & 255, c = threadIdx.x;
  const float ce = cemb[b];
  s1[c] = silu_f(ce * aw1[l * 128 + c] + ab1[l * 128 + c]);
  __syncthreads();
  float a = ab2[l * 128 + c];
  for (int k = 0; k < 128; ++k) a += s1[k] * aw2[(l * 128 + k) * 128 + c];
  s2[c] = silu_f(a);
  __syncthreads();
  float o = 0.f;
  for (int k = 0; k < 128; ++k) o += s2[k] * mixin[(l * 128 + k) * 128 + c];
  call[((size_t)l * 256 + b) * 128 + c] = o;
}

// h0 = concat(emb[atom_types], z[graph]) @ W_latent + b_latent
__global__ __launch_bounds__(256) void k_h0(
    const int* __restrict__ at, const int* __restrict__ n2g,
    const float* __restrict__ emb, const float* __restrict__ z,
    const float* __restrict__ Wl, const float* __restrict__ bl,
    float* __restrict__ h, u16* __restrict__ hbf) {
  const int c = threadIdx.x & 127, half = threadIdx.x >> 7;
  const int n0 = blockIdx.x * 8 + half * 4;
  const int a0 = at[n0 + 0], a1 = at[n0 + 1], a2 = at[n0 + 2], a3 = at[n0 + 3];
  const int g0 = n2g[n0 + 0], g1 = n2g[n0 + 1], g2 = n2g[n0 + 2], g3 = n2g[n0 + 3];
  float s0 = bl[c], s1 = s0, s2 = s0, s3 = s0;
  for (int k = 0; k < 128; ++k) {
    const float w = Wl[k * 128 + c];
    s0 += emb[a0 * 128 + k] * w;
    s1 += emb[a1 * 128 + k] * w;
    s2 += emb[a2 * 128 + k] * w;
    s3 += emb[a3 * 128 + k] * w;
  }
  for (int k = 0; k < 256; ++k) {
    const float w = Wl[(128 + k) * 128 + c];
    s0 += z[g0 * 256 + k] * w;
    s1 += z[g1 * 256 + k] * w;
    s2 += z[g2 * 256 + k] * w;
    s3 += z[g3 * 256 + k] * w;
  }
  h[(n0 + 0) * 128 + c] = s0; hbf[(n0 + 0) * 128 + c] = f2bf(s0);
  h[(n0 + 1) * 128 + c] = s1; hbf[(n0 + 1) * 128 + c] = f2bf(s1);
  h[(n0 + 2) * 128 + c] = s2; hbf[(n0 + 2) * 128 + c] = f2bf(s2);
  h[(n0 + 3) * 128 + c] = s3; hbf[(n0 + 3) * 128 + c] = f2bf(s3);
}

// ---------------------------------------------------------------------------
// Edge MLP (the hot kernel): 64 edges/block, bf16 MFMA 16x16x32
//   einp = [h[src](128) | h[dst](128) | sin-emb(60) | lat_ips(9) | pad->352]
//   t1 = silu(einp@w1+b1); ef = silu(t1@w2+b2); atomic scatter-add by src
// ---------------------------------------------------------------------------
__global__ __launch_bounds__(256, 2) void k_edge(
    const u16* __restrict__ hbf, const float* __restrict__ fc,
    const int* __restrict__ ei, const int* __restrict__ n2g,
    const float* __restrict__ lip,
    const u16* __restrict__ wt1, const u16* __restrict__ wt2,
    const float* __restrict__ eb1, const float* __restrict__ eb2,
    float* __restrict__ agg) {
  __shared__ u16 einp[64][360];   // row stride 720B: 16B aligned, 2-way-free banks
  __shared__ u16 t1s[64][136];    // row stride 272B
  __shared__ int srcs[64];
  const int tid = threadIdx.x;
  const int e0 = blockIdx.x * 64;

  { // staging: 4 threads per edge
    const int m = tid >> 2, p = tid & 3;
    const int e = e0 + m;
    const int s = ei[e], d = ei[EE + e];
    if (p == 0) srcs[m] = s;
    const uint4* hs = (const uint4*)(hbf + (size_t)s * HH);
    const uint4* hd = (const uint4*)(hbf + (size_t)d * HH);
    uint4* ra = (uint4*)(&einp[m][0]);
    uint4* rb = (uint4*)(&einp[m][128]);
#pragma unroll
    for (int q = 0; q < 4; ++q) { ra[p * 4 + q] = hs[p * 4 + q]; rb[p * 4 + q] = hd[p * 4 + q]; }
    if (p < 3) {
      float dd = fc[d * 3 + p] - fc[s * 3 + p];
      dd -= floorf(dd);                      // (dst-src) mod 1.0 in [0,1)
#pragma unroll
      for (int k = 0; k < 10; ++k) {
        float sv, cv;
        __sincosf(dd * (6.28318530717958647692f * (float)k), &sv, &cv);
        einp[m][256 + p * 10 + k] = f2bf(sv);
        einp[m][286 + p * 10 + k] = f2bf(cv);
      }
    } else {
      const int g = n2g[s];
#pragma unroll
      for (int j = 0; j < 9; ++j) einp[m][316 + j] = f2bf(lip[g * 9 + j]);
#pragma unroll
      for (int j = 325; j < 360; ++j) einp[m][j] = 0;
    }
  }
  __syncthreads();

  const int lane = tid & 63;
  const int w = tid >> 6;
  const int wm = w >> 1, wn = w & 1;       // 2x2 wave grid: 32 edges x 64 cols each
  const int lr = lane & 15;                 // A row-in-tile / B col-in-tile
  const int lk = (lane >> 4) * 8;           // k sub-offset
  const int rr = (lane >> 4) * 4;           // C/D row base

  // GEMM1: (64 x 352) @ (352 x 128)
  f32x4 acc[2][4] = {};
  for (int kb = 0; kb < 11; ++kb) {
    bf16x8 a0 = *(const bf16x8*)(&einp[wm * 32 + lr][kb * 32 + lk]);
    bf16x8 a1 = *(const bf16x8*)(&einp[wm * 32 + 16 + lr][kb * 32 + lk]);
#pragma unroll
    for (int nt = 0; nt < 4; ++nt) {
      const int col = wn * 64 + nt * 16 + lr;
      bf16x8 b = *(const bf16x8*)(wt1 + col * 352 + kb * 32 + lk);
      acc[0][nt] = __builtin_amdgcn_mfma_f32_16x16x32_bf16(a0, b, acc[0][nt], 0, 0, 0);
      acc[1][nt] = __builtin_amdgcn_mfma_f32_16x16x32_bf16(a1, b, acc[1][nt], 0, 0, 0);
    }
  }
#pragma unroll
  for (int mt = 0; mt < 2; ++mt)
#pragma unroll
    for (int nt = 0; nt < 4; ++nt) {
      const int col = wn * 64 + nt * 16 + lr;
      const float bias = eb1[col];
#pragma unroll
      for (int r = 0; r < 4; ++r) {
        const int row = wm * 32 + mt * 16 + rr + r;
        t1s[row][col] = f2bf(silu_f(acc[mt][nt][r] + bias));
      }
    }
  __syncthreads();

  // GEMM2: (64 x 128) @ (128 x 128)
  f32x4 acc2[2][4] = {};
  for (int kb = 0; kb < 4; ++kb) {
    bf16x8 a0 = *(const bf16x8*)(&t1s[wm * 32 + lr][kb * 32 + lk]);
    bf16x8 a1 = *(const bf16x8*)(&t1s[wm * 32 + 16 + lr][kb * 32 + lk]);
#pragma unroll
    for (int nt = 0; nt < 4; ++nt) {
      const int col = wn * 64 + nt * 16 + lr;
      bf16x8 b = *(const bf16x8*)(wt2 + col * 128 + kb * 32 + lk);
      acc2[0][nt] = __builtin_amdgcn_mfma_f32_16x16x32_bf16(a0, b, acc2[0][nt], 0, 0, 0);
      acc2[1][nt] = __builtin_amdgcn_mfma_f32_16x16x32_bf16(a1, b, acc2[1][nt], 0, 0, 0);
    }
  }
#pragma unroll
  for (int mt = 0; mt < 2; ++mt)
#pragma unroll
    for (int nt = 0; nt < 4; ++nt) {
      const int col = wn * 64 + nt * 16 + lr;
      const float bias = eb2[col];
#pragma unroll
      for (int r = 0; r < 4; ++r) {
        const int row = wm * 32 + mt * 16 + rr + r;
        const float v = silu_f(acc2[mt][nt][r] + bias);
        unsafeAtomicAdd(&agg[(size_t)srcs[row] * HH + col], v);
      }
    }
}

// ---------------------------------------------------------------------------
// Node MLP + residual + conditional add, in-place on h (fp32), refresh h bf16
// ---------------------------------------------------------------------------
__global__ __launch_bounds__(256) void k_node(
    float* __restrict__ h, const float* __restrict__ agg, const int* __restrict__ cnt,
    const float* __restrict__ nw1, const float* __restrict__ nb1,
    const float* __restrict__ nw2, const float* __restrict__ nb2,
    const float* __restrict__ cl, const int* __restrict__ n2g,
    u16* __restrict__ hbf) {
  __shared__ float t1s[8][128];
  const int c = threadIdx.x & 127, half = threadIdx.x >> 7;
  const int n0 = blockIdx.x * 8 + half * 4;
  float a0 = nb1[c], a1 = a0, a2 = a0, a3 = a0;
  for (int k = 0; k < 128; ++k) {
    const float w = nw1[k * 128 + c];
    a0 += h[(n0 + 0) * 128 + k] * w;
    a1 += h[(n0 + 1) * 128 + k] * w;
    a2 += h[(n0 + 2) * 128 + k] * w;
    a3 += h[(n0 + 3) * 128 + k] * w;
  }
  const float i0 = 1.f / fmaxf((float)cnt[n0 + 0], 1.f);
  const float i1 = 1.f / fmaxf((float)cnt[n0 + 1], 1.f);
  const float i2 = 1.f / fmaxf((float)cnt[n0 + 2], 1.f);
  const float i3 = 1.f / fmaxf((float)cnt[n0 + 3], 1.f);
  for (int k = 0; k < 128; ++k) {
    const float w = nw1[(128 + k) * 128 + c];
    a0 += agg[(n0 + 0) * 128 + k] * i0 * w;
    a1 += agg[(n0 + 1) * 128 + k] * i1 * w;
    a2 += agg[(n0 + 2) * 128 + k] * i2 * w;
    a3 += agg[(n0 + 3) * 128 + k] * i3 * w;
  }
  t1s[half * 4 + 0][c] = silu_f(a0);
  t1s[half * 4 + 1][c] = silu_f(a1);
  t1s[half * 4 + 2][c] = silu_f(a2);
  t1s[half * 4 + 3][c] = silu_f(a3);
  __syncthreads();
  const float b2 = nb2[c];
  float d0 = b2, d1 = b2, d2 = b2, d3 = b2;
  for (int k = 0; k < 128; ++k) {
    const float w = nw2[k * 128 + c];
    d0 += t1s[half * 4 + 0][k] * w;
    d1 += t1s[half * 4 + 1][k] * w;
    d2 += t1s[half * 4 + 2][k] * w;
    d3 += t1s[half * 4 + 3][k] * w;
  }
  {
    const float r0 = h[(n0 + 0) * 128 + c] + silu_f(d0) + cl[n2g[n0 + 0] * 128 + c];
    const float r1 = h[(n0 + 1) * 128 + c] + silu_f(d1) + cl[n2g[n0 + 1] * 128 + c];
    const float r2 = h[(n0 + 2) * 128 + c] + silu_f(d2) + cl[n2g[n0 + 2] * 128 + c];
    const float r3 = h[(n0 + 3) * 128 + c] + silu_f(d3) + cl[n2g[n0 + 3] * 128 + c];
    h[(n0 + 0) * 128 + c] = r0; hbf[(n0 + 0) * 128 + c] = f2bf(r0);
    h[(n0 + 1) * 128 + c] = r1; hbf[(n0 + 1) * 128 + c] = f2bf(r1);
    h[(n0 + 2) * 128 + c] = r2; hbf[(n0 + 2) * 128 + c] = f2bf(r2);
    h[(n0 + 3) * 128 + c] = r3; hbf[(n0 + 3) * 128 + c] = f2bf(r3);
  }
}

// ---------------------------------------------------------------------------
// Output heads
// ---------------------------------------------------------------------------
__global__ __launch_bounds__(256) void k_coord(
    const float* __restrict__ h, const float* __restrict__ Wc, float* __restrict__ out) {
  const int idx = blockIdx.x * 256 + threadIdx.x;   // N*3
  if (idx >= NN * 3) return;
  const int n = idx / 3, j = idx % 3;
  float s = 0.f;
  for (int k = 0; k < 128; ++k) s += h[n * 128 + k] * Wc[k * 3 + j];
  out[BB * 9 + idx] = s;
}

__global__ __launch_bounds__(128) void k_lattice(
    const float* __restrict__ h, const float* __restrict__ Wl9,
    const float* __restrict__ lat, float* __restrict__ out) {
  __shared__ float gf[128];
  __shared__ float lo[9];
  const int b = blockIdx.x, c = threadIdx.x;
  float s = 0.f;
  for (int m = 0; m < 32; ++m) s += h[((size_t)b * 32 + m) * 128 + c];
  gf[c] = s * (1.f / 32.f);                 // node2graph = repeat(arange(B),32)
  __syncthreads();
  if (c < 9) {
    float t = 0.f;
    for (int k = 0; k < 128; ++k) t += gf[k] * Wl9[k * 9 + c];
    lo[c] = t;
  }
  __syncthreads();
  if (c < 9) {
    const int i = c / 3, kk = c % 3;
    float t = 0.f;
#pragma unroll
    for (int j = 0; j < 3; ++j) t += lo[i * 3 + j] * lat[b * 9 + j * 3 + kk];
    out[b * 9 + c] = t;
  }
}

// ---------------------------------------------------------------------------
extern "C" void kernel_launch(void* const* d_in, const int* in_sizes, int n_in,
                              void* d_out, int out_size, void* d_ws, size_t ws_size,
                              hipStream_t stream) {
  const int*   atom_types = (const int*)  d_in[0];
  const float* frac       = (const float*)d_in[1];
  const float* lattices   = (const float*)d_in[2];
  const float* z          = (const float*)d_in[3];
  const float* cemb       = (const float*)d_in[4];
  const int*   ei         = (const int*)  d_in[5];
  const int*   n2g        = (const int*)  d_in[6];
  const float* emb        = (const float*)d_in[7];
  const float* W_lat      = (const float*)d_in[8];
  const float* b_lat      = (const float*)d_in[9];
  const float* ew1        = (const float*)d_in[10];
  const float* eb1        = (const float*)d_in[11];
  const float* ew2        = (const float*)d_in[12];
  const float* eb2        = (const float*)d_in[13];
  const float* nw1        = (const float*)d_in[14];
  const float* nb1        = (const float*)d_in[15];
  const float* nw2        = (const float*)d_in[16];
  const float* nb2        = (const float*)d_in[17];
  const float* mixin      = (const float*)d_in[18];
  const float* aw1        = (const float*)d_in[19];
  const float* ab1        = (const float*)d_in[20];
  const float* aw2        = (const float*)d_in[21];
  const float* ab2        = (const float*)d_in[22];
  const float* Wc         = (const float*)d_in[23];
  const float* Wl9        = (const float*)d_in[24];
  float* out = (float*)d_out;

  uint8_t* base = (uint8_t*)d_ws;
  size_t off = 0;
  auto carve = [&](size_t bytes) -> void* {
    void* r = base + off;
    off = (off + bytes + 255) & ~(size_t)255;
    return r;
  };
  float* h    = (float*)carve((size_t)NN * HH * 4);
  u16*   hbf  = (u16*)  carve((size_t)NN * HH * 2);
  float* agg  = (float*)carve((size_t)NN * HH * 4);
  int*   cnt  = (int*)  carve((size_t)NN * 4);
  float* lip  = (float*)carve((size_t)BB * 9 * 4);
  float* call = (float*)carve((size_t)LL * BB * HH * 4);
  u16*   wt1  = (u16*)  carve((size_t)LL * 128 * 352 * 2);
  u16*   wt2  = (u16*)  carve((size_t)LL * 128 * 128 * 2);

  hipMemsetAsync(cnt, 0, (size_t)NN * 4, stream);
  k_hist<<<EE / 256, 256, 0, stream>>>(ei, cnt);
  k_latips<<<(BB * 9 + 255) / 256, 256, 0, stream>>>(lattices, lip);
  k_wt1<<<(LL * 128 * 352) / 256, 256, 0, stream>>>(ew1, wt1);
  k_wt2<<<(LL * 128 * 128) / 256, 256, 0, stream>>>(ew2, wt2);
  k_adapt<<<LL * BB, 128, 0, stream>>>(cemb, aw1, ab1, aw2, ab2, mixin, call);
  k_h0<<<NN / 8, 256, 0, stream>>>(atom_types, n2g, emb, z, W_lat, b_lat, h, hbf);

  for (int l = 0; l < LL; ++l) {
    hipMemsetAsync(agg, 0, (size_t)NN * HH * 4, stream);
    k_edge<<<EE / 64, 256, 0, stream>>>(hbf, frac, ei, n2g, lip,
        wt1 + (size_t)l * 128 * 352, wt2 + (size_t)l * 128 * 128,
        eb1 + l * 128, eb2 + l * 128, agg);
    k_node<<<NN / 8, 256, 0, stream>>>(h, agg, cnt,
        nw1 + (size_t)l * 256 * 128, nb1 + l * 128,
        nw2 + (size_t)l * 128 * 128, nb2 + l * 128,
        call + (size_t)l * BB * HH, n2g, hbf);
  }

  k_coord<<<(NN * 3) / 256, 256, 0, stream>>>(h, Wc, out);
  k_lattice<<<BB, 128, 0, stream>>>(h, Wl9, lattices, out);
}

// Round 2
// 611.343 us; speedup vs baseline: 1.1491x; 1.1491x over previous
//
#include <hip/hip_runtime.h>
#include <hip/hip_bf16.h>
#include <stdint.h>

#define NN 8192
#define BB 256
#define EE 163840
#define HH 128
#define ZZ 256
#define LL 4

typedef unsigned short u16;
typedef float  f32x4  __attribute__((ext_vector_type(4)));
typedef __bf16 bf16x8 __attribute__((ext_vector_type(8)));

__device__ __forceinline__ u16 f2bf(float f) {
  union { float f; uint32_t u; } v; v.f = f;
  uint32_t r = v.u + 0x7fffu + ((v.u >> 16) & 1u);   // RNE, NaN not expected
  return (u16)(r >> 16);
}
__device__ __forceinline__ float silu_f(float x) {
  return x / (1.0f + __expf(-x));
}

// ---------------------------------------------------------------------------
// Edge sorting prep: histogram -> exclusive scan -> scatter (counting sort)
// ---------------------------------------------------------------------------
__global__ void k_hist(const int* __restrict__ ei, int* __restrict__ cnt) {
  const int e = blockIdx.x * 256 + threadIdx.x;
  if (e < EE) atomicAdd(&cnt[ei[e]], 1);
}

__global__ __launch_bounds__(1024) void k_scan(const int* __restrict__ cnt,
                                               int* __restrict__ ofs,
                                               int* __restrict__ cursor) {
  __shared__ int part[1024];
  const int t = threadIdx.x;
  int v[8]; int s = 0;
#pragma unroll
  for (int j = 0; j < 8; ++j) { v[j] = s; s += cnt[t * 8 + j]; }
  part[t] = s;
  __syncthreads();
  for (int d = 1; d < 1024; d <<= 1) {
    int x = (t >= d) ? part[t - d] : 0;
    __syncthreads();
    part[t] += x;
    __syncthreads();
  }
  const int base = (t == 0) ? 0 : part[t - 1];
#pragma unroll
  for (int j = 0; j < 8; ++j) {
    const int o = base + v[j];
    ofs[t * 8 + j] = o;
    cursor[t * 8 + j] = o;
  }
}

__global__ void k_scatter(const int* __restrict__ ei, int* __restrict__ cursor,
                          int* __restrict__ perm) {
  const int e = blockIdx.x * 256 + threadIdx.x;
  if (e < EE) {
    const int s = ei[e];
    const int p = atomicAdd(&cursor[s], 1);
    perm[p] = e;
  }
}

// ---------------------------------------------------------------------------
// Small prep kernels
// ---------------------------------------------------------------------------
__global__ void k_latips(const float* __restrict__ lat, float* __restrict__ lip) {
  const int idx = blockIdx.x * 256 + threadIdx.x;
  if (idx >= BB * 9) return;
  const int b = idx / 9, j = idx % 9, i = j / 3, kk = j % 3;
  float s = 0.f;
#pragma unroll
  for (int m = 0; m < 3; ++m) s += lat[b * 9 + i * 3 + m] * lat[b * 9 + kk * 3 + m];
  lip[idx] = s;
}

// transpose edge weights to [n][k] bf16, K padded 325->352 with zeros
__global__ void k_wt1(const float* __restrict__ ew1, u16* __restrict__ wt1) {
  const int idx = blockIdx.x * 256 + threadIdx.x;   // L*128*352
  if (idx >= LL * 128 * 352) return;
  const int l = idx / (128 * 352), rem = idx % (128 * 352);
  const int n = rem / 352, k = rem % 352;
  wt1[idx] = (k < 325) ? f2bf(ew1[((size_t)l * 325 + k) * 128 + n]) : (u16)0;
}
__global__ void k_wt2(const float* __restrict__ ew2, u16* __restrict__ wt2) {
  const int idx = blockIdx.x * 256 + threadIdx.x;   // L*128*128
  if (idx >= LL * 128 * 128) return;
  const int l = idx >> 14, rem = idx & 16383;
  const int n = rem >> 7, k = rem & 127;
  wt2[idx] = f2bf(ew2[((size_t)l * 128 + k) * 128 + n]);
}

// per-layer, per-graph conditional adapter: c = silu(silu(cemb*w1+b1)@w2+b2)@mixin
__global__ __launch_bounds__(128) void k_adapt(
    const float* __restrict__ cemb, const float* __restrict__ aw1,
    const float* __restrict__ ab1, const float* __restrict__ aw2,
    const float* __restrict__ ab2, const float* __restrict__ mixin,
    float* __restrict__ call) {
  __shared__ float s1[128], s2[128];
  const int l = blockIdx.x >> 8, b = blockIdx.x & 255, c = threadIdx.x;
  const float ce = cemb[b];
  s1[c] = silu_f(ce * aw1[l * 128 + c] + ab1[l * 128 + c]);
  __syncthreads();
  float a = ab2[l * 128 + c];
  for (int k = 0; k < 128; ++k) a += s1[k] * aw2[(l * 128 + k) * 128 + c];
  s2[c] = silu_f(a);
  __syncthreads();
  float o = 0.f;
  for (int k = 0; k < 128; ++k) o += s2[k] * mixin[(l * 128 + k) * 128 + c];
  call[((size_t)l * 256 + b) * 128 + c] = o;
}

// h0 = concat(emb[atom_types], z[graph]) @ W_latent + b_latent
__global__ __launch_bounds__(256) void k_h0(
    const int* __restrict__ at, const int* __restrict__ n2g,
    const float* __restrict__ emb, const float* __restrict__ z,
    const float* __restrict__ Wl, const float* __restrict__ bl,
    float* __restrict__ h, u16* __restrict__ hbf) {
  const int c = threadIdx.x & 127, half = threadIdx.x >> 7;
  const int n0 = blockIdx.x * 8 + half * 4;
  const int a0 = at[n0 + 0], a1 = at[n0 + 1], a2 = at[n0 + 2], a3 = at[n0 + 3];
  const int g0 = n2g[n0 + 0], g1 = n2g[n0 + 1], g2 = n2g[n0 + 2], g3 = n2g[n0 + 3];
  float s0 = bl[c], s1 = s0, s2 = s0, s3 = s0;
  for (int k = 0; k < 128; ++k) {
    const float w = Wl[k * 128 + c];
    s0 += emb[a0 * 128 + k] * w;
    s1 += emb[a1 * 128 + k] * w;
    s2 += emb[a2 * 128 + k] * w;
    s3 += emb[a3 * 128 + k] * w;
  }
  for (int k = 0; k < 256; ++k) {
    const float w = Wl[(128 + k) * 128 + c];
    s0 += z[g0 * 256 + k] * w;
    s1 += z[g1 * 256 + k] * w;
    s2 += z[g2 * 256 + k] * w;
    s3 += z[g3 * 256 + k] * w;
  }
  h[(n0 + 0) * 128 + c] = s0; hbf[(n0 + 0) * 128 + c] = f2bf(s0);
  h[(n0 + 1) * 128 + c] = s1; hbf[(n0 + 1) * 128 + c] = f2bf(s1);
  h[(n0 + 2) * 128 + c] = s2; hbf[(n0 + 2) * 128 + c] = f2bf(s2);
  h[(n0 + 3) * 128 + c] = s3; hbf[(n0 + 3) * 128 + c] = f2bf(s3);
}

// ---------------------------------------------------------------------------
// Edge MLP (hot kernel): 64 sorted edges/block, bf16 MFMA 16x16x32,
// in-block segmented reduction by src, boundary atomics only.
// ---------------------------------------------------------------------------
__global__ __launch_bounds__(256, 2) void k_edge(
    const u16* __restrict__ hbf, const float* __restrict__ fc,
    const int* __restrict__ ei, const int* __restrict__ n2g,
    const float* __restrict__ lip, const int* __restrict__ perm,
    const u16* __restrict__ wt1, const u16* __restrict__ wt2,
    const float* __restrict__ eb1, const float* __restrict__ eb2,
    float* __restrict__ agg) {
  __shared__ char smem_raw[64 * 360 * 2];          // einp (bf16) / efs (f32) overlay
  u16   (*einp)[360] = (u16(*)[360])smem_raw;      // 46080 B
  float (*efs)[130]  = (float(*)[130])smem_raw;    // 33280 B (after GEMM1 done)
  __shared__ u16 t1s[64][136];                     // 17408 B
  __shared__ int srcs[64];
  const int tid = threadIdx.x;
  const int e0 = blockIdx.x * 64;

  { // staging: 4 threads per edge
    const int m = tid >> 2, p = tid & 3;
    const int e = perm[e0 + m];
    const int s = ei[e], d = ei[EE + e];
    if (p == 0) srcs[m] = s;
    const uint4* hs = (const uint4*)(hbf + (size_t)s * HH);
    const uint4* hd = (const uint4*)(hbf + (size_t)d * HH);
    uint4* ra = (uint4*)(&einp[m][0]);
    uint4* rb = (uint4*)(&einp[m][128]);
#pragma unroll
    for (int q = 0; q < 4; ++q) { ra[p * 4 + q] = hs[p * 4 + q]; rb[p * 4 + q] = hd[p * 4 + q]; }
    if (p < 3) {
      float dd = fc[d * 3 + p] - fc[s * 3 + p];
      dd -= floorf(dd);                      // (dst-src) mod 1.0 in [0,1)
      float s1, c1;
      __sincosf(dd * 6.28318530717958647692f, &s1, &c1);
      einp[m][256 + p * 10 + 0] = 0;                 // sin(0)
      einp[m][286 + p * 10 + 0] = f2bf(1.0f);        // cos(0)
      float sk = s1, ck = c1;
#pragma unroll
      for (int k = 1; k < 10; ++k) {
        einp[m][256 + p * 10 + k] = f2bf(sk);
        einp[m][286 + p * 10 + k] = f2bf(ck);
        const float sn = sk * c1 + ck * s1;          // angle addition
        const float cn = ck * c1 - sk * s1;
        sk = sn; ck = cn;
      }
    } else {
      const int g = n2g[s];
#pragma unroll
      for (int j = 0; j < 9; ++j) einp[m][316 + j] = f2bf(lip[g * 9 + j]);
#pragma unroll
      for (int j = 325; j < 360; ++j) einp[m][j] = 0;
    }
  }
  __syncthreads();

  const int lane = tid & 63;
  const int w = tid >> 6;
  const int wm = w >> 1, wn = w & 1;        // 2x2 wave grid: 32 edges x 64 cols
  const int lr = lane & 15;                 // A row-in-tile / B col-in-tile
  const int lk = (lane >> 4) * 8;           // k sub-offset
  const int rr = (lane >> 4) * 4;           // C/D row base

  // GEMM1: (64 x 352) @ (352 x 128)
  f32x4 acc[2][4] = {};
  for (int kb = 0; kb < 11; ++kb) {
    bf16x8 a0 = *(const bf16x8*)(&einp[wm * 32 + lr][kb * 32 + lk]);
    bf16x8 a1 = *(const bf16x8*)(&einp[wm * 32 + 16 + lr][kb * 32 + lk]);
#pragma unroll
    for (int nt = 0; nt < 4; ++nt) {
      const int col = wn * 64 + nt * 16 + lr;
      bf16x8 b = *(const bf16x8*)(wt1 + col * 352 + kb * 32 + lk);
      acc[0][nt] = __builtin_amdgcn_mfma_f32_16x16x32_bf16(a0, b, acc[0][nt], 0, 0, 0);
      acc[1][nt] = __builtin_amdgcn_mfma_f32_16x16x32_bf16(a1, b, acc[1][nt], 0, 0, 0);
    }
  }
#pragma unroll
  for (int mt = 0; mt < 2; ++mt)
#pragma unroll
    for (int nt = 0; nt < 4; ++nt) {
      const int col = wn * 64 + nt * 16 + lr;
      const float bias = eb1[col];
#pragma unroll
      for (int r = 0; r < 4; ++r) {
        const int row = wm * 32 + mt * 16 + rr + r;
        t1s[row][col] = f2bf(silu_f(acc[mt][nt][r] + bias));
      }
    }
  __syncthreads();   // t1s ready; einp reads complete -> efs overlay safe after GEMM2

  // GEMM2: (64 x 128) @ (128 x 128)
  f32x4 acc2[2][4] = {};
  for (int kb = 0; kb < 4; ++kb) {
    bf16x8 a0 = *(const bf16x8*)(&t1s[wm * 32 + lr][kb * 32 + lk]);
    bf16x8 a1 = *(const bf16x8*)(&t1s[wm * 32 + 16 + lr][kb * 32 + lk]);
#pragma unroll
    for (int nt = 0; nt < 4; ++nt) {
      const int col = wn * 64 + nt * 16 + lr;
      bf16x8 b = *(const bf16x8*)(wt2 + col * 128 + kb * 32 + lk);
      acc2[0][nt] = __builtin_amdgcn_mfma_f32_16x16x32_bf16(a0, b, acc2[0][nt], 0, 0, 0);
      acc2[1][nt] = __builtin_amdgcn_mfma_f32_16x16x32_bf16(a1, b, acc2[1][nt], 0, 0, 0);
    }
  }
#pragma unroll
  for (int mt = 0; mt < 2; ++mt)
#pragma unroll
    for (int nt = 0; nt < 4; ++nt) {
      const int col = wn * 64 + nt * 16 + lr;
      const float bias = eb2[col];
#pragma unroll
      for (int r = 0; r < 4; ++r) {
        const int row = wm * 32 + mt * 16 + rr + r;
        efs[row][col] = silu_f(acc2[mt][nt][r] + bias);
      }
    }
  __syncthreads();

  // segmented reduction over sorted srcs: 2 threads per col, 32 rows each
  {
    const int col = tid & 127, seg = tid >> 7;
    const int r0 = seg * 32;
    int cur = srcs[r0];
    float a = 0.f;
#pragma unroll 4
    for (int r = 0; r < 32; ++r) {
      const int s = srcs[r0 + r];           // wave-uniform
      if (s != cur) {
        unsafeAtomicAdd(&agg[(size_t)cur * HH + col], a);
        cur = s; a = 0.f;
      }
      a += efs[r0 + r][col];
    }
    unsafeAtomicAdd(&agg[(size_t)cur * HH + col], a);
  }
}

// ---------------------------------------------------------------------------
// Node MLP + residual + conditional add, in-place on h (fp32), refresh h bf16.
// Also zeroes agg rows after use (replaces per-layer memset).
// ---------------------------------------------------------------------------
__global__ __launch_bounds__(256) void k_node(
    float* __restrict__ h, float* __restrict__ agg, const int* __restrict__ cnt,
    const float* __restrict__ nw1, const float* __restrict__ nb1,
    const float* __restrict__ nw2, const float* __restrict__ nb2,
    const float* __restrict__ cl, const int* __restrict__ n2g,
    u16* __restrict__ hbf) {
  __shared__ float t1s[8][128];
  const int c = threadIdx.x & 127, half = threadIdx.x >> 7;
  const int n0 = blockIdx.x * 8 + half * 4;
  float a0 = nb1[c], a1 = a0, a2 = a0, a3 = a0;
  for (int k = 0; k < 128; ++k) {
    const float w = nw1[k * 128 + c];
    a0 += h[(n0 + 0) * 128 + k] * w;
    a1 += h[(n0 + 1) * 128 + k] * w;
    a2 += h[(n0 + 2) * 128 + k] * w;
    a3 += h[(n0 + 3) * 128 + k] * w;
  }
  const float i0 = 1.f / fmaxf((float)cnt[n0 + 0], 1.f);
  const float i1 = 1.f / fmaxf((float)cnt[n0 + 1], 1.f);
  const float i2 = 1.f / fmaxf((float)cnt[n0 + 2], 1.f);
  const float i3 = 1.f / fmaxf((float)cnt[n0 + 3], 1.f);
  for (int k = 0; k < 128; ++k) {
    const float w = nw1[(128 + k) * 128 + c];
    a0 += agg[(n0 + 0) * 128 + k] * i0 * w;
    a1 += agg[(n0 + 1) * 128 + k] * i1 * w;
    a2 += agg[(n0 + 2) * 128 + k] * i2 * w;
    a3 += agg[(n0 + 3) * 128 + k] * i3 * w;
  }
  t1s[half * 4 + 0][c] = silu_f(a0);
  t1s[half * 4 + 1][c] = silu_f(a1);
  t1s[half * 4 + 2][c] = silu_f(a2);
  t1s[half * 4 + 3][c] = silu_f(a3);
  __syncthreads();
  // all agg reads for this block's rows are done -> zero for next layer
  agg[(n0 + 0) * 128 + c] = 0.f;
  agg[(n0 + 1) * 128 + c] = 0.f;
  agg[(n0 + 2) * 128 + c] = 0.f;
  agg[(n0 + 3) * 128 + c] = 0.f;
  const float b2 = nb2[c];
  float d0 = b2, d1 = b2, d2 = b2, d3 = b2;
  for (int k = 0; k < 128; ++k) {
    const float w = nw2[k * 128 + c];
    d0 += t1s[half * 4 + 0][k] * w;
    d1 += t1s[half * 4 + 1][k] * w;
    d2 += t1s[half * 4 + 2][k] * w;
    d3 += t1s[half * 4 + 3][k] * w;
  }
  {
    const float r0 = h[(n0 + 0) * 128 + c] + silu_f(d0) + cl[n2g[n0 + 0] * 128 + c];
    const float r1 = h[(n0 + 1) * 128 + c] + silu_f(d1) + cl[n2g[n0 + 1] * 128 + c];
    const float r2 = h[(n0 + 2) * 128 + c] + silu_f(d2) + cl[n2g[n0 + 2] * 128 + c];
    const float r3 = h[(n0 + 3) * 128 + c] + silu_f(d3) + cl[n2g[n0 + 3] * 128 + c];
    h[(n0 + 0) * 128 + c] = r0; hbf[(n0 + 0) * 128 + c] = f2bf(r0);
    h[(n0 + 1) * 128 + c] = r1; hbf[(n0 + 1) * 128 + c] = f2bf(r1);
    h[(n0 + 2) * 128 + c] = r2; hbf[(n0 + 2) * 128 + c] = f2bf(r2);
    h[(n0 + 3) * 128 + c] = r3; hbf[(n0 + 3) * 128 + c] = f2bf(r3);
  }
}

// ---------------------------------------------------------------------------
// Output heads
// ---------------------------------------------------------------------------
__global__ __launch_bounds__(256) void k_coord(
    const float* __restrict__ h, const float* __restrict__ Wc, float* __restrict__ out) {
  const int idx = blockIdx.x * 256 + threadIdx.x;   // N*3
  if (idx >= NN * 3) return;
  const int n = idx / 3, j = idx % 3;
  float s = 0.f;
  for (int k = 0; k < 128; ++k) s += h[n * 128 + k] * Wc[k * 3 + j];
  out[BB * 9 + idx] = s;
}

__global__ __launch_bounds__(128) void k_lattice(
    const float* __restrict__ h, const float* __restrict__ Wl9,
    const float* __restrict__ lat, float* __restrict__ out) {
  __shared__ float gf[128];
  __shared__ float lo[9];
  const int b = blockIdx.x, c = threadIdx.x;
  float s = 0.f;
  for (int m = 0; m < 32; ++m) s += h[((size_t)b * 32 + m) * 128 + c];
  gf[c] = s * (1.f / 32.f);                 // node2graph = repeat(arange(B),32)
  __syncthreads();
  if (c < 9) {
    float t = 0.f;
    for (int k = 0; k < 128; ++k) t += gf[k] * Wl9[k * 9 + c];
    lo[c] = t;
  }
  __syncthreads();
  if (c < 9) {
    const int i = c / 3, kk = c % 3;
    float t = 0.f;
#pragma unroll
    for (int j = 0; j < 3; ++j) t += lo[i * 3 + j] * lat[b * 9 + j * 3 + kk];
    out[b * 9 + c] = t;
  }
}

// ---------------------------------------------------------------------------
extern "C" void kernel_launch(void* const* d_in, const int* in_sizes, int n_in,
                              void* d_out, int out_size, void* d_ws, size_t ws_size,
                              hipStream_t stream) {
  const int*   atom_types = (const int*)  d_in[0];
  const float* frac       = (const float*)d_in[1];
  const float* lattices   = (const float*)d_in[2];
  const float* z          = (const float*)d_in[3];
  const float* cemb       = (const float*)d_in[4];
  const int*   ei         = (const int*)  d_in[5];
  const int*   n2g        = (const int*)  d_in[6];
  const float* emb        = (const float*)d_in[7];
  const float* W_lat      = (const float*)d_in[8];
  const float* b_lat      = (const float*)d_in[9];
  const float* ew1        = (const float*)d_in[10];
  const float* eb1        = (const float*)d_in[11];
  const float* ew2        = (const float*)d_in[12];
  const float* eb2        = (const float*)d_in[13];
  const float* nw1        = (const float*)d_in[14];
  const float* nb1        = (const float*)d_in[15];
  const float* nw2        = (const float*)d_in[16];
  const float* nb2        = (const float*)d_in[17];
  const float* mixin      = (const float*)d_in[18];
  const float* aw1        = (const float*)d_in[19];
  const float* ab1        = (const float*)d_in[20];
  const float* aw2        = (const float*)d_in[21];
  const float* ab2        = (const float*)d_in[22];
  const float* Wc         = (const float*)d_in[23];
  const float* Wl9        = (const float*)d_in[24];
  float* out = (float*)d_out;

  uint8_t* base = (uint8_t*)d_ws;
  size_t off = 0;
  auto carve = [&](size_t bytes) -> void* {
    void* r = base + off;
    off = (off + bytes + 255) & ~(size_t)255;
    return r;
  };
  float* h      = (float*)carve((size_t)NN * HH * 4);
  u16*   hbf    = (u16*)  carve((size_t)NN * HH * 2);
  float* agg    = (float*)carve((size_t)NN * HH * 4);
  int*   cnt    = (int*)  carve((size_t)NN * 4);
  int*   ofs    = (int*)  carve((size_t)NN * 4);
  int*   cursor = (int*)  carve((size_t)NN * 4);
  int*   perm   = (int*)  carve((size_t)EE * 4);
  float* lip    = (float*)carve((size_t)BB * 9 * 4);
  float* call   = (float*)carve((size_t)LL * BB * HH * 4);
  u16*   wt1    = (u16*)  carve((size_t)LL * 128 * 352 * 2);
  u16*   wt2    = (u16*)  carve((size_t)LL * 128 * 128 * 2);

  hipMemsetAsync(cnt, 0, (size_t)NN * 4, stream);
  k_hist<<<EE / 256, 256, 0, stream>>>(ei, cnt);
  k_scan<<<1, 1024, 0, stream>>>(cnt, ofs, cursor);
  k_scatter<<<EE / 256, 256, 0, stream>>>(ei, cursor, perm);
  k_latips<<<(BB * 9 + 255) / 256, 256, 0, stream>>>(lattices, lip);
  k_wt1<<<(LL * 128 * 352) / 256, 256, 0, stream>>>(ew1, wt1);
  k_wt2<<<(LL * 128 * 128) / 256, 256, 0, stream>>>(ew2, wt2);
  k_adapt<<<LL * BB, 128, 0, stream>>>(cemb, aw1, ab1, aw2, ab2, mixin, call);
  k_h0<<<NN / 8, 256, 0, stream>>>(atom_types, n2g, emb, z, W_lat, b_lat, h, hbf);
  hipMemsetAsync(agg, 0, (size_t)NN * HH * 4, stream);  // layers 1..3 zeroed by k_node

  for (int l = 0; l < LL; ++l) {
    k_edge<<<EE / 64, 256, 0, stream>>>(hbf, frac, ei, n2g, lip, perm,
        wt1 + (size_t)l * 128 * 352, wt2 + (size_t)l * 128 * 128,
        eb1 + l * 128, eb2 + l * 128, agg);
    k_node<<<NN / 8, 256, 0, stream>>>(h, agg, cnt,
        nw1 + (size_t)l * 256 * 128, nb1 + l * 128,
        nw2 + (size_t)l * 128 * 128, nb2 + l * 128,
        call + (size_t)l * BB * HH, n2g, hbf);
  }

  k_coord<<<(NN * 3) / 256, 256, 0, stream>>>(h, Wc, out);
  k_lattice<<<BB, 128, 0, stream>>>(h, Wl9, lattices, out);
}

// Round 3
// 573.497 us; speedup vs baseline: 1.2249x; 1.0660x over previous
//
#include <hip/hip_runtime.h>
#include <hip/hip_bf16.h>
#include <stdint.h>

#define NN 8192
#define BB 256
#define EE 163840
#define HH 128
#define ZZ 256
#define LL 4
#define TPB 10          // edge tiles (of 64) per block; 256 blocks * 10 * 64 = EE

typedef unsigned short u16;
typedef float  f32x4  __attribute__((ext_vector_type(4)));
typedef __bf16 bf16x8 __attribute__((ext_vector_type(8)));

__device__ __forceinline__ u16 f2bf(float f) {
  union { float f; uint32_t u; } v; v.f = f;
  uint32_t r = v.u + 0x7fffu + ((v.u >> 16) & 1u);   // RNE
  return (u16)(r >> 16);
}
__device__ __forceinline__ float silu_f(float x) {
  return x / (1.0f + __expf(-x));
}

// ---------------------------------------------------------------------------
// Edge sorting prep: histogram -> exclusive scan -> scatter (counting sort)
// ---------------------------------------------------------------------------
__global__ void k_hist(const int* __restrict__ ei, int* __restrict__ cnt) {
  const int e = blockIdx.x * 256 + threadIdx.x;
  if (e < EE) atomicAdd(&cnt[ei[e]], 1);
}

__global__ __launch_bounds__(1024) void k_scan(const int* __restrict__ cnt,
                                               int* __restrict__ cursor) {
  __shared__ int part[1024];
  const int t = threadIdx.x;
  int v[8]; int s = 0;
#pragma unroll
  for (int j = 0; j < 8; ++j) { v[j] = s; s += cnt[t * 8 + j]; }
  part[t] = s;
  __syncthreads();
  for (int d = 1; d < 1024; d <<= 1) {
    int x = (t >= d) ? part[t - d] : 0;
    __syncthreads();
    part[t] += x;
    __syncthreads();
  }
  const int base = (t == 0) ? 0 : part[t - 1];
#pragma unroll
  for (int j = 0; j < 8; ++j) cursor[t * 8 + j] = base + v[j];
}

__global__ void k_scatter(const int* __restrict__ ei, int* __restrict__ cursor,
                          int* __restrict__ perm) {
  const int e = blockIdx.x * 256 + threadIdx.x;
  if (e < EE) {
    const int s = ei[e];
    const int ppos = atomicAdd(&cursor[s], 1);
    perm[ppos] = e;
  }
}

// ---------------------------------------------------------------------------
// Small prep kernels
// ---------------------------------------------------------------------------
__global__ void k_latips(const float* __restrict__ lat, float* __restrict__ lip) {
  const int idx = blockIdx.x * 256 + threadIdx.x;
  if (idx >= BB * 9) return;
  const int b = idx / 9, j = idx % 9, i = j / 3, kk = j % 3;
  float s = 0.f;
#pragma unroll
  for (int mm = 0; mm < 3; ++mm) s += lat[b * 9 + i * 3 + mm] * lat[b * 9 + kk * 3 + mm];
  lip[b * 12 + j] = s;          // padded stride 12 for float4 loads
}

// transpose edge weights to [n][k] bf16, K padded 325->352 with zeros
__global__ void k_wt1(const float* __restrict__ ew1, u16* __restrict__ wt1) {
  const int idx = blockIdx.x * 256 + threadIdx.x;   // L*128*352
  if (idx >= LL * 128 * 352) return;
  const int l = idx / (128 * 352), rem = idx % (128 * 352);
  const int n = rem / 352, k = rem % 352;
  wt1[idx] = (k < 325) ? f2bf(ew1[((size_t)l * 325 + k) * 128 + n]) : (u16)0;
}
__global__ void k_wt2(const float* __restrict__ ew2, u16* __restrict__ wt2) {
  const int idx = blockIdx.x * 256 + threadIdx.x;   // L*128*128
  if (idx >= LL * 128 * 128) return;
  const int l = idx >> 14, rem = idx & 16383;
  const int n = rem >> 7, k = rem & 127;
  wt2[idx] = f2bf(ew2[((size_t)l * 128 + k) * 128 + n]);
}

// per-layer, per-graph conditional adapter: c = silu(silu(cemb*w1+b1)@w2+b2)@mixin
__global__ __launch_bounds__(128) void k_adapt(
    const float* __restrict__ cemb, const float* __restrict__ aw1,
    const float* __restrict__ ab1, const float* __restrict__ aw2,
    const float* __restrict__ ab2, const float* __restrict__ mixin,
    float* __restrict__ call) {
  __shared__ float s1[128], s2[128];
  const int l = blockIdx.x >> 8, b = blockIdx.x & 255, c = threadIdx.x;
  const float ce = cemb[b];
  s1[c] = silu_f(ce * aw1[l * 128 + c] + ab1[l * 128 + c]);
  __syncthreads();
  float a = ab2[l * 128 + c];
  for (int k = 0; k < 128; ++k) a += s1[k] * aw2[(l * 128 + k) * 128 + c];
  s2[c] = silu_f(a);
  __syncthreads();
  float o = 0.f;
  for (int k = 0; k < 128; ++k) o += s2[k] * mixin[(l * 128 + k) * 128 + c];
  call[((size_t)l * 256 + b) * 128 + c] = o;
}

// h0 = concat(emb[atom_types], z[graph]) @ W_latent + b_latent
__global__ __launch_bounds__(256) void k_h0(
    const int* __restrict__ at, const int* __restrict__ n2g,
    const float* __restrict__ emb, const float* __restrict__ z,
    const float* __restrict__ Wl, const float* __restrict__ bl,
    float* __restrict__ h, u16* __restrict__ hbf) {
  const int c = threadIdx.x & 127, half = threadIdx.x >> 7;
  const int n0 = blockIdx.x * 8 + half * 4;
  const int a0 = at[n0 + 0], a1 = at[n0 + 1], a2 = at[n0 + 2], a3 = at[n0 + 3];
  const int g0 = n2g[n0 + 0], g1 = n2g[n0 + 1], g2 = n2g[n0 + 2], g3 = n2g[n0 + 3];
  float s0 = bl[c], s1 = s0, s2 = s0, s3 = s0;
  for (int k = 0; k < 128; ++k) {
    const float w = Wl[k * 128 + c];
    s0 += emb[a0 * 128 + k] * w;
    s1 += emb[a1 * 128 + k] * w;
    s2 += emb[a2 * 128 + k] * w;
    s3 += emb[a3 * 128 + k] * w;
  }
  for (int k = 0; k < 256; ++k) {
    const float w = Wl[(128 + k) * 128 + c];
    s0 += z[g0 * 256 + k] * w;
    s1 += z[g1 * 256 + k] * w;
    s2 += z[g2 * 256 + k] * w;
    s3 += z[g3 * 256 + k] * w;
  }
  h[(n0 + 0) * 128 + c] = s0; hbf[(n0 + 0) * 128 + c] = f2bf(s0);
  h[(n0 + 1) * 128 + c] = s1; hbf[(n0 + 1) * 128 + c] = f2bf(s1);
  h[(n0 + 2) * 128 + c] = s2; hbf[(n0 + 2) * 128 + c] = f2bf(s2);
  h[(n0 + 3) * 128 + c] = s3; hbf[(n0 + 3) * 128 + c] = f2bf(s3);
}

// ---------------------------------------------------------------------------
// Edge MLP: persistent-weight, double-buffered, 8 waves (2M x 4N), 10 tiles.
// ---------------------------------------------------------------------------
__global__ __launch_bounds__(512, 2) void k_edge(
    const u16* __restrict__ hbf, const float* __restrict__ fc,
    const int* __restrict__ ei, const int* __restrict__ n2g,
    const float* __restrict__ lip, const int* __restrict__ perm,
    const u16* __restrict__ wt1, const u16* __restrict__ wt2,
    const float* __restrict__ eb1, const float* __restrict__ eb2,
    float* __restrict__ agg) {
  // einp bf16 [64][360] rows of 720B; efs f32 [64][180] rows of 720B overlay.
  // efs uses only cols 0..127 (bytes 0..511) -> einp cols 256..359 survive.
  __shared__ __align__(16) char ebuf[2][64 * 720];
  __shared__ __bf16 t1s[64][136];
  __shared__ int srcs[2][64];

  const int tid = threadIdx.x;
  const int lane = tid & 63, w = tid >> 6;
  const int wm = w >> 2, wn = w & 3;          // 2 row-halves x 4 col-quarters
  const int lr = lane & 15, lk = (lane >> 4) * 8, rr = (lane >> 4) * 4;
  const int m = tid >> 3, p = tid & 7;        // staging: 8 threads per edge

  // persistent weight fragments (per wave: 32 cols x full K) + biases
  bf16x8 b1f[2][11], b2f[2][4];
  float bias1[2], bias2[2];
#pragma unroll
  for (int nt = 0; nt < 2; ++nt) {
    const int col = wn * 32 + nt * 16 + lr;
#pragma unroll
    for (int kb = 0; kb < 11; ++kb)
      b1f[nt][kb] = *(const bf16x8*)(wt1 + (size_t)col * 352 + kb * 32 + lk);
#pragma unroll
    for (int kb = 0; kb < 4; ++kb)
      b2f[nt][kb] = *(const bf16x8*)(wt2 + (size_t)col * 128 + kb * 32 + lk);
    bias1[nt] = eb1[col];
    bias2[nt] = eb2[col];
  }

  const int tile0 = blockIdx.x * TPB;

  // zero einp pad cols [325,360) once (never clobbered by efs overlay)
  for (int i = tid; i < 2 * 64 * 35; i += 512) {
    const int b = i / (64 * 35), rem = i % (64 * 35);
    ((__bf16(*)[360])ebuf[b])[rem / 35][325 + rem % 35] = (__bf16)0.0f;
  }

  // prologue: stage tile0 -> buf0 (synchronous)
  {
    __bf16 (*en)[360] = (__bf16(*)[360])ebuf[0];
    const int e = perm[tile0 * 64 + m];
    const int s = ei[e], d = ei[EE + e];
    if (p == 0) srcs[0][m] = s;
    const uint4* hs = (const uint4*)(hbf + (size_t)s * HH);
    const uint4* hd = (const uint4*)(hbf + (size_t)d * HH);
    *(uint4*)(&en[m][p * 16])       = hs[p * 2];
    *(uint4*)(&en[m][p * 16 + 8])   = hs[p * 2 + 1];
    *(uint4*)(&en[m][128 + p * 16])     = hd[p * 2];
    *(uint4*)(&en[m][128 + p * 16 + 8]) = hd[p * 2 + 1];
    if (p < 3) {
      float dd = fc[d * 3 + p] - fc[s * 3 + p];
      dd -= floorf(dd);
      float s1, c1;
      __sincosf(dd * 6.2831853071795864769f, &s1, &c1);
      en[m][256 + p * 10] = (__bf16)0.0f;
      en[m][286 + p * 10] = (__bf16)1.0f;
      float sk = s1, ck = c1;
#pragma unroll
      for (int k = 1; k < 10; ++k) {
        en[m][256 + p * 10 + k] = (__bf16)sk;
        en[m][286 + p * 10 + k] = (__bf16)ck;
        const float sn = sk * c1 + ck * s1, cn = ck * c1 - sk * s1;
        sk = sn; ck = cn;
      }
    } else if (p == 3) {
      const float4* Lp = (const float4*)(lip + (size_t)n2g[s] * 12);
      const float4 lA = Lp[0], lB = Lp[1], lC = Lp[2];
      en[m][316] = (__bf16)lA.x; en[m][317] = (__bf16)lA.y;
      en[m][318] = (__bf16)lA.z; en[m][319] = (__bf16)lA.w;
      en[m][320] = (__bf16)lB.x; en[m][321] = (__bf16)lB.y;
      en[m][322] = (__bf16)lB.z; en[m][323] = (__bf16)lB.w;
      en[m][324] = (__bf16)lC.x;
    }
  }
  __syncthreads();

  for (int t = 0; t < TPB; ++t) {
    const int cur = t & 1, nxt = cur ^ 1;
    __bf16 (*einp)[360] = (__bf16(*)[360])ebuf[cur];
    float  (*efs)[180]  = (float(*)[180])ebuf[cur];

    // T14 issue-early: gather next tile into registers (latency hides under GEMM1)
    const bool has_next = (t + 1 < TPB);
    uint4 h0, h1, h2, h3;
    float f_d = 0.f, f_s = 0.f;
    float4 lA, lB, lC;
    int s_next = 0;
    if (has_next) {
      const int e = perm[(tile0 + t + 1) * 64 + m];
      s_next = ei[e];
      const int d = ei[EE + e];
      const uint4* hs = (const uint4*)(hbf + (size_t)s_next * HH);
      const uint4* hd = (const uint4*)(hbf + (size_t)d * HH);
      h0 = hs[p * 2]; h1 = hs[p * 2 + 1];
      h2 = hd[p * 2]; h3 = hd[p * 2 + 1];
      if (p < 3) { f_d = fc[d * 3 + p]; f_s = fc[s_next * 3 + p]; }
      else if (p == 3) {
        const float4* Lp = (const float4*)(lip + (size_t)n2g[s_next] * 12);
        lA = Lp[0]; lB = Lp[1]; lC = Lp[2];
      }
    }

    // GEMM1: (64 x 352) @ (352 x 128), A from LDS, B from registers
    f32x4 acc[2][2] = {};
#pragma unroll
    for (int kb = 0; kb < 11; ++kb) {
      bf16x8 a0 = *(const bf16x8*)(&einp[wm * 32 + lr][kb * 32 + lk]);
      bf16x8 a1 = *(const bf16x8*)(&einp[wm * 32 + 16 + lr][kb * 32 + lk]);
#pragma unroll
      for (int nt = 0; nt < 2; ++nt) {
        acc[0][nt] = __builtin_amdgcn_mfma_f32_16x16x32_bf16(a0, b1f[nt][kb], acc[0][nt], 0, 0, 0);
        acc[1][nt] = __builtin_amdgcn_mfma_f32_16x16x32_bf16(a1, b1f[nt][kb], acc[1][nt], 0, 0, 0);
      }
    }
#pragma unroll
    for (int mt = 0; mt < 2; ++mt)
#pragma unroll
      for (int nt = 0; nt < 2; ++nt) {
        const int col = wn * 32 + nt * 16 + lr;
#pragma unroll
        for (int r = 0; r < 4; ++r)
          t1s[wm * 32 + mt * 16 + rr + r][col] = (__bf16)silu_f(acc[mt][nt][r] + bias1[nt]);
      }

    // finish staging: write gathered regs into einp[nxt]
    if (has_next) {
      __bf16 (*en)[360] = (__bf16(*)[360])ebuf[nxt];
      if (p == 0) srcs[nxt][m] = s_next;
      *(uint4*)(&en[m][p * 16])       = h0;
      *(uint4*)(&en[m][p * 16 + 8])   = h1;
      *(uint4*)(&en[m][128 + p * 16])     = h2;
      *(uint4*)(&en[m][128 + p * 16 + 8]) = h3;
      if (p < 3) {
        float dd = f_d - f_s;
        dd -= floorf(dd);
        float s1, c1;
        __sincosf(dd * 6.2831853071795864769f, &s1, &c1);
        en[m][256 + p * 10] = (__bf16)0.0f;
        en[m][286 + p * 10] = (__bf16)1.0f;
        float sk = s1, ck = c1;
#pragma unroll
        for (int k = 1; k < 10; ++k) {
          en[m][256 + p * 10 + k] = (__bf16)sk;
          en[m][286 + p * 10 + k] = (__bf16)ck;
          const float sn = sk * c1 + ck * s1, cn = ck * c1 - sk * s1;
          sk = sn; ck = cn;
        }
      } else if (p == 3) {
        en[m][316] = (__bf16)lA.x; en[m][317] = (__bf16)lA.y;
        en[m][318] = (__bf16)lA.z; en[m][319] = (__bf16)lA.w;
        en[m][320] = (__bf16)lB.x; en[m][321] = (__bf16)lB.y;
        en[m][322] = (__bf16)lB.z; en[m][323] = (__bf16)lB.w;
        en[m][324] = (__bf16)lC.x;
      }
    }
    __syncthreads();   // t1s ready; einp[cur] fully read; staging writes landed

    // GEMM2: (64 x 128) @ (128 x 128)
    f32x4 acc2[2][2] = {};
#pragma unroll
    for (int kb = 0; kb < 4; ++kb) {
      bf16x8 a0 = *(const bf16x8*)(&t1s[wm * 32 + lr][kb * 32 + lk]);
      bf16x8 a1 = *(const bf16x8*)(&t1s[wm * 32 + 16 + lr][kb * 32 + lk]);
#pragma unroll
      for (int nt = 0; nt < 2; ++nt) {
        acc2[0][nt] = __builtin_amdgcn_mfma_f32_16x16x32_bf16(a0, b2f[nt][kb], acc2[0][nt], 0, 0, 0);
        acc2[1][nt] = __builtin_amdgcn_mfma_f32_16x16x32_bf16(a1, b2f[nt][kb], acc2[1][nt], 0, 0, 0);
      }
    }
#pragma unroll
    for (int mt = 0; mt < 2; ++mt)
#pragma unroll
      for (int nt = 0; nt < 2; ++nt) {
        const int col = wn * 32 + nt * 16 + lr;
#pragma unroll
        for (int r = 0; r < 4; ++r)
          efs[wm * 32 + mt * 16 + rr + r][col] = silu_f(acc2[mt][nt][r] + bias2[nt]);
      }
    __syncthreads();   // efs ready

    // segmented reduction: 4 segments of 16 rows, 128 cols
    {
      const int col = tid & 127, seg = tid >> 7, r0 = seg * 16;
      const int* sr = srcs[cur];
      int curS = sr[r0];
      float a = 0.f;
#pragma unroll 4
      for (int r = 0; r < 16; ++r) {
        const int s = sr[r0 + r];
        if (s != curS) {
          unsafeAtomicAdd(&agg[(size_t)curS * HH + col], a);
          curS = s; a = 0.f;
        }
        a += efs[r0 + r][col];
      }
      unsafeAtomicAdd(&agg[(size_t)curS * HH + col], a);
    }
    __syncthreads();   // reduce done; buffers may be reused next iteration
  }
}

// ---------------------------------------------------------------------------
// Node MLP + residual + conditional add, in-place on h (fp32), refresh h bf16.
// Also zeroes agg rows after use (replaces per-layer memset).
// ---------------------------------------------------------------------------
__global__ __launch_bounds__(256) void k_node(
    float* __restrict__ h, float* __restrict__ agg, const int* __restrict__ cnt,
    const float* __restrict__ nw1, const float* __restrict__ nb1,
    const float* __restrict__ nw2, const float* __restrict__ nb2,
    const float* __restrict__ cl, const int* __restrict__ n2g,
    u16* __restrict__ hbf) {
  __shared__ float t1s[8][128];
  const int c = threadIdx.x & 127, half = threadIdx.x >> 7;
  const int n0 = blockIdx.x * 8 + half * 4;
  float a0 = nb1[c], a1 = a0, a2 = a0, a3 = a0;
  for (int k = 0; k < 128; ++k) {
    const float w = nw1[k * 128 + c];
    a0 += h[(n0 + 0) * 128 + k] * w;
    a1 += h[(n0 + 1) * 128 + k] * w;
    a2 += h[(n0 + 2) * 128 + k] * w;
    a3 += h[(n0 + 3) * 128 + k] * w;
  }
  const float i0 = 1.f / fmaxf((float)cnt[n0 + 0], 1.f);
  const float i1 = 1.f / fmaxf((float)cnt[n0 + 1], 1.f);
  const float i2 = 1.f / fmaxf((float)cnt[n0 + 2], 1.f);
  const float i3 = 1.f / fmaxf((float)cnt[n0 + 3], 1.f);
  for (int k = 0; k < 128; ++k) {
    const float w = nw1[(128 + k) * 128 + c];
    a0 += agg[(n0 + 0) * 128 + k] * i0 * w;
    a1 += agg[(n0 + 1) * 128 + k] * i1 * w;
    a2 += agg[(n0 + 2) * 128 + k] * i2 * w;
    a3 += agg[(n0 + 3) * 128 + k] * i3 * w;
  }
  t1s[half * 4 + 0][c] = silu_f(a0);
  t1s[half * 4 + 1][c] = silu_f(a1);
  t1s[half * 4 + 2][c] = silu_f(a2);
  t1s[half * 4 + 3][c] = silu_f(a3);
  __syncthreads();
  agg[(n0 + 0) * 128 + c] = 0.f;
  agg[(n0 + 1) * 128 + c] = 0.f;
  agg[(n0 + 2) * 128 + c] = 0.f;
  agg[(n0 + 3) * 128 + c] = 0.f;
  const float b2 = nb2[c];
  float d0 = b2, d1 = b2, d2 = b2, d3 = b2;
  for (int k = 0; k < 128; ++k) {
    const float w = nw2[k * 128 + c];
    d0 += t1s[half * 4 + 0][k] * w;
    d1 += t1s[half * 4 + 1][k] * w;
    d2 += t1s[half * 4 + 2][k] * w;
    d3 += t1s[half * 4 + 3][k] * w;
  }
  {
    const float r0 = h[(n0 + 0) * 128 + c] + silu_f(d0) + cl[n2g[n0 + 0] * 128 + c];
    const float r1 = h[(n0 + 1) * 128 + c] + silu_f(d1) + cl[n2g[n0 + 1] * 128 + c];
    const float r2 = h[(n0 + 2) * 128 + c] + silu_f(d2) + cl[n2g[n0 + 2] * 128 + c];
    const float r3 = h[(n0 + 3) * 128 + c] + silu_f(d3) + cl[n2g[n0 + 3] * 128 + c];
    h[(n0 + 0) * 128 + c] = r0; hbf[(n0 + 0) * 128 + c] = f2bf(r0);
    h[(n0 + 1) * 128 + c] = r1; hbf[(n0 + 1) * 128 + c] = f2bf(r1);
    h[(n0 + 2) * 128 + c] = r2; hbf[(n0 + 2) * 128 + c] = f2bf(r2);
    h[(n0 + 3) * 128 + c] = r3; hbf[(n0 + 3) * 128 + c] = f2bf(r3);
  }
}

// ---------------------------------------------------------------------------
// Output heads
// ---------------------------------------------------------------------------
__global__ __launch_bounds__(256) void k_coord(
    const float* __restrict__ h, const float* __restrict__ Wc, float* __restrict__ out) {
  const int idx = blockIdx.x * 256 + threadIdx.x;   // N*3
  if (idx >= NN * 3) return;
  const int n = idx / 3, j = idx % 3;
  float s = 0.f;
  for (int k = 0; k < 128; ++k) s += h[n * 128 + k] * Wc[k * 3 + j];
  out[BB * 9 + idx] = s;
}

__global__ __launch_bounds__(128) void k_lattice(
    const float* __restrict__ h, const float* __restrict__ Wl9,
    const float* __restrict__ lat, float* __restrict__ out) {
  __shared__ float gf[128];
  __shared__ float lo[9];
  const int b = blockIdx.x, c = threadIdx.x;
  float s = 0.f;
  for (int mm = 0; mm < 32; ++mm) s += h[((size_t)b * 32 + mm) * 128 + c];
  gf[c] = s * (1.f / 32.f);
  __syncthreads();
  if (c < 9) {
    float t = 0.f;
    for (int k = 0; k < 128; ++k) t += gf[k] * Wl9[k * 9 + c];
    lo[c] = t;
  }
  __syncthreads();
  if (c < 9) {
    const int i = c / 3, kk = c % 3;
    float t = 0.f;
#pragma unroll
    for (int j = 0; j < 3; ++j) t += lo[i * 3 + j] * lat[b * 9 + j * 3 + kk];
    out[b * 9 + c] = t;
  }
}

// ---------------------------------------------------------------------------
extern "C" void kernel_launch(void* const* d_in, const int* in_sizes, int n_in,
                              void* d_out, int out_size, void* d_ws, size_t ws_size,
                              hipStream_t stream) {
  const int*   atom_types = (const int*)  d_in[0];
  const float* frac       = (const float*)d_in[1];
  const float* lattices   = (const float*)d_in[2];
  const float* z          = (const float*)d_in[3];
  const float* cemb       = (const float*)d_in[4];
  const int*   ei         = (const int*)  d_in[5];
  const int*   n2g        = (const int*)  d_in[6];
  const float* emb        = (const float*)d_in[7];
  const float* W_lat      = (const float*)d_in[8];
  const float* b_lat      = (const float*)d_in[9];
  const float* ew1        = (const float*)d_in[10];
  const float* eb1        = (const float*)d_in[11];
  const float* ew2        = (const float*)d_in[12];
  const float* eb2        = (const float*)d_in[13];
  const float* nw1        = (const float*)d_in[14];
  const float* nb1        = (const float*)d_in[15];
  const float* nw2        = (const float*)d_in[16];
  const float* nb2        = (const float*)d_in[17];
  const float* mixin      = (const float*)d_in[18];
  const float* aw1        = (const float*)d_in[19];
  const float* ab1        = (const float*)d_in[20];
  const float* aw2        = (const float*)d_in[21];
  const float* ab2        = (const float*)d_in[22];
  const float* Wc         = (const float*)d_in[23];
  const float* Wl9        = (const float*)d_in[24];
  float* out = (float*)d_out;

  uint8_t* base = (uint8_t*)d_ws;
  size_t off = 0;
  auto carve = [&](size_t bytes) -> void* {
    void* r = base + off;
    off = (off + bytes + 255) & ~(size_t)255;
    return r;
  };
  float* h      = (float*)carve((size_t)NN * HH * 4);
  u16*   hbf    = (u16*)  carve((size_t)NN * HH * 2);
  float* agg    = (float*)carve((size_t)NN * HH * 4);
  int*   cnt    = (int*)  carve((size_t)NN * 4);
  int*   cursor = (int*)  carve((size_t)NN * 4);
  int*   perm   = (int*)  carve((size_t)EE * 4);
  float* lip    = (float*)carve((size_t)BB * 12 * 4);
  float* call   = (float*)carve((size_t)LL * BB * HH * 4);
  u16*   wt1    = (u16*)  carve((size_t)LL * 128 * 352 * 2);
  u16*   wt2    = (u16*)  carve((size_t)LL * 128 * 128 * 2);

  hipMemsetAsync(cnt, 0, (size_t)NN * 4, stream);
  k_hist<<<EE / 256, 256, 0, stream>>>(ei, cnt);
  k_scan<<<1, 1024, 0, stream>>>(cnt, cursor);
  k_scatter<<<EE / 256, 256, 0, stream>>>(ei, cursor, perm);
  k_latips<<<(BB * 9 + 255) / 256, 256, 0, stream>>>(lattices, lip);
  k_wt1<<<(LL * 128 * 352) / 256, 256, 0, stream>>>(ew1, wt1);
  k_wt2<<<(LL * 128 * 128) / 256, 256, 0, stream>>>(ew2, wt2);
  k_adapt<<<LL * BB, 128, 0, stream>>>(cemb, aw1, ab1, aw2, ab2, mixin, call);
  k_h0<<<NN / 8, 256, 0, stream>>>(atom_types, n2g, emb, z, W_lat, b_lat, h, hbf);
  hipMemsetAsync(agg, 0, (size_t)NN * HH * 4, stream);  // layers 1..3 zeroed by k_node

  for (int l = 0; l < LL; ++l) {
    k_edge<<<256, 512, 0, stream>>>(hbf, frac, ei, n2g, lip, perm,
        wt1 + (size_t)l * 128 * 352, wt2 + (size_t)l * 128 * 128,
        eb1 + l * 128, eb2 + l * 128, agg);
    k_node<<<NN / 8, 256, 0, stream>>>(h, agg, cnt,
        nw1 + (size_t)l * 256 * 128, nb1 + l * 128,
        nw2 + (size_t)l * 128 * 128, nb2 + l * 128,
        call + (size_t)l * BB * HH, n2g, hbf);
  }

  k_coord<<<(NN * 3) / 256, 256, 0, stream>>>(h, Wc, out);
  k_lattice<<<BB, 128, 0, stream>>>(h, Wl9, lattices, out);
}